// Round 1
// 612.907 us; speedup vs baseline: 1.0630x; 1.0630x over previous
//
#include <hip/hip_runtime.h>

#define HH 50
#define TT 1024
#define BT 16            // batch tile per block (MFMA M)
#define NB (2048 / BT)   // 128 blocks
#define CHUNK 256        // x staging chunk (timesteps)
#define XST 260          // x LDS row stride (floats)
#define HST 72           // h LDS row stride (f16 elems)

typedef _Float16 half8 __attribute__((ext_vector_type(8)));
typedef float f32x4 __attribute__((ext_vector_type(4)));

union H8 { half8 v; _Float16 h[8]; unsigned short u[8]; unsigned int i[4]; };

__device__ __forceinline__ float rcp_f(float x) { return __builtin_amdgcn_rcpf(x); }

#if __has_builtin(__builtin_amdgcn_exp2f)
__device__ __forceinline__ float exp2_f(float x) { return __builtin_amdgcn_exp2f(x); }
#else
__device__ __forceinline__ float exp2_f(float x) { return __expf(0.6931471805599453f * x); }
#endif

#define L2E   1.4426950408889634f
#define L2E2  2.8853900817779268f

// weights pre-scaled: i,f,o rows by -log2e; g rows by +2*log2e
__device__ __forceinline__ float sigm_n(float a) {   // sigmoid(x), a = -x*log2e
    return rcp_f(1.0f + exp2_f(a));
}
__device__ __forceinline__ float tanh_p(float a) {   // tanh(x), a = 2x*log2e
    return __builtin_fmaf(-2.0f, rcp_f(1.0f + exp2_f(a)), 1.0f);
}
__device__ __forceinline__ unsigned short f2h(float f) {
    return __builtin_bit_cast(unsigned short, (_Float16)f);
}

__global__ __launch_bounds__(512) void lstm_mfma_kernel(
    const float* __restrict__ x,
    const float* __restrict__ wih1, const float* __restrict__ whh1,
    const float* __restrict__ bih1, const float* __restrict__ bhh1,
    const float* __restrict__ wih2,
    const float* __restrict__ bih2, const float* __restrict__ bhh2,
    const float* __restrict__ fcw,  const float* __restrict__ fcb,
    float* __restrict__ out)
{
    __shared__ float xs[BT * XST];                       // 16.6 KB
    __shared__ __align__(16) unsigned short hb[2][BT * HST]; // 4.6 KB (f16 bits)
    __shared__ float h2s[BT * 52];                       // 3.3 KB

    const int tid  = threadIdx.x;
    const int wv   = tid >> 6;        // 0..7
    const int js   = wv & 3;          // j-slice 0..3
    const int bh   = wv >> 2;         // batch half 0..1
    const int lane = tid & 63;
    const int l16  = lane & 15;
    const int quad = lane >> 4;
    const int j    = js * 16 + l16;   // padded gate sub-index 0..63
    const bool jv  = (j < HH);
    const bool q2  = (quad == 2);
    const int b0   = blockIdx.x * BT;

    // ---- persistent per-lane weights: Whh B-frags (f16, gate-folded scale) ----
    // K layout: k=0..49 Whh; k=50 <- Wih (x slot); k=51 <- bias_hi; k=52 <- bias_lo
    H8 bw[4][2];
    #pragma unroll
    for (int t4 = 0; t4 < 4; ++t4) {
        const float sc = (t4 == 2) ? L2E2 : -L2E;
        const int row = t4 * HH + j;
        #pragma unroll
        for (int kk = 0; kk < 2; ++kk)
            #pragma unroll
            for (int e = 0; e < 8; ++e) {
                const int k = kk * 32 + quad * 8 + e;
                const float v = (jv && k < HH) ? whh1[row * HH + k] * sc : 0.0f;
                bw[t4][kk].h[e] = (_Float16)v;
            }
        if (q2) {
            const float bsc = jv ? (bih1[row] + bhh1[row]) * sc : 0.0f;
            const _Float16 bhi = (_Float16)bsc;
            bw[t4][1].h[2] = (_Float16)(jv ? wih1[row] * sc : 0.0f); // k=50
            bw[t4][1].h[3] = bhi;                                    // k=51
            bw[t4][1].h[4] = (_Float16)(bsc - (float)bhi);           // k=52
        }
    }

    // zero initial h buffer
    for (int i = tid; i < BT * HST; i += 512) hb[0][i] = 0;

    float c0 = 0.f, c1 = 0.f;
    unsigned short* cur = hb[0];
    unsigned short* nxt = hb[1];
    const f32x4 kZ = {0.f, 0.f, 0.f, 0.f};
    const int r0 = bh * 2;            // this wave's accumulator rows r0, r0+1
    float xv = 0.f;

    for (int t = 0; t < TT; ++t) {
        const int tc = t & (CHUNK - 1);
        if (tc == 0) {
            for (int i = tid; i < BT * (CHUNK / 4); i += 512) {
                const int r = i >> 6, c4 = i & 63;
                const float4 q = ((const float4*)x)[((b0 + r) * TT + t) / 4 + c4];
                *(float4*)&xs[r * XST + c4 * 4] = q;
            }
            __syncthreads();          // also covers hb[0] zeroing at t==0
            xv = xs[l16 * XST];       // reload after restage
        }

        // A-frag patch words: (x_t|1.0) at k=50,51 and (1.0|0) at k=52,53
        const unsigned int pk  = 0x3c000000u | (unsigned int)f2h(xv);
        H8 a0, a1;
        a0.v = *(const half8*)&cur[l16 * HST + quad * 8];
        a1.v = *(const half8*)&cur[l16 * HST + 32 + quad * 8];
        a1.i[1] = q2 ? pk : a1.i[1];
        a1.i[2] = q2 ? 0x00003c00u : a1.i[2];

        f32x4 acc[4];
        #pragma unroll
        for (int t4 = 0; t4 < 4; ++t4)
            acc[t4] = __builtin_amdgcn_mfma_f32_16x16x32_f16(a0.v, bw[t4][0].v, kZ, 0, 0, 0);
        #pragma unroll
        for (int t4 = 0; t4 < 4; ++t4)
            acc[t4] = __builtin_amdgcn_mfma_f32_16x16x32_f16(a1.v, bw[t4][1].v, acc[t4], 0, 0, 0);

        // prefetch next-step x (off critical path; stale at chunk end, reloaded above)
        xv = xs[l16 * XST + ((tc + 1) & (CHUNK - 1))];

        // gate math only for this wave's 2 batch rows
        {
            const float ig = sigm_n(acc[0][r0]);
            const float fg = sigm_n(acc[1][r0]);
            const float gg = tanh_p(acc[2][r0]);
            const float og = sigm_n(acc[3][r0]);
            c0 = __builtin_fmaf(fg, c0, ig * gg);
            nxt[(quad * 4 + r0) * HST + j] = f2h(og * tanh_p(c0 * L2E2));
        }
        {
            const float ig = sigm_n(acc[0][r0 + 1]);
            const float fg = sigm_n(acc[1][r0 + 1]);
            const float gg = tanh_p(acc[2][r0 + 1]);
            const float og = sigm_n(acc[3][r0 + 1]);
            c1 = __builtin_fmaf(fg, c1, ig * gg);
            nxt[(quad * 4 + r0 + 1) * HST + j] = f2h(og * tanh_p(c1 * L2E2));
        }

        unsigned short* tmp = cur; cur = nxt; nxt = tmp;
        __syncthreads();
    }

    // ---- LSTM2: one cell step from zero state, input = h1 (in `cur`) ----
    if (bh == 0) {
        H8 bw2[4][2];
        float b2[4];
        #pragma unroll
        for (int t4 = 0; t4 < 4; ++t4) {
            const float sc = (t4 == 2) ? L2E2 : -L2E;
            const int row = t4 * HH + j;
            #pragma unroll
            for (int kk = 0; kk < 2; ++kk)
                #pragma unroll
                for (int e = 0; e < 8; ++e) {
                    const int k = kk * 32 + quad * 8 + e;
                    const float v = (jv && k < HH) ? wih2[row * HH + k] * sc : 0.0f;
                    bw2[t4][kk].h[e] = (_Float16)v;
                }
            b2[t4] = jv ? (bih2[row] + bhh2[row]) * sc : 0.0f;
        }
        H8 a0, a1;
        a0.v = *(const half8*)&cur[l16 * HST + quad * 8];
        a1.v = *(const half8*)&cur[l16 * HST + 32 + quad * 8];
        f32x4 acc2[4];
        #pragma unroll
        for (int t4 = 0; t4 < 4; ++t4) {
            const f32x4 cb = {b2[t4], b2[t4], b2[t4], b2[t4]};
            acc2[t4] = __builtin_amdgcn_mfma_f32_16x16x32_f16(a0.v, bw2[t4][0].v, cb, 0, 0, 0);
            acc2[t4] = __builtin_amdgcn_mfma_f32_16x16x32_f16(a1.v, bw2[t4][1].v, acc2[t4], 0, 0, 0);
        }
        #pragma unroll
        for (int r = 0; r < 4; ++r) {
            const float ig = sigm_n(acc2[0][r]);
            const float gg = tanh_p(acc2[2][r]);
            const float og = sigm_n(acc2[3][r]);
            const float cc = ig * gg;            // f*c0 term vanishes (c0 = 0)
            const float h2 = og * tanh_p(cc * L2E2);
            if (jv) h2s[(quad * 4 + r) * 52 + j] = h2;
        }
    }
    __syncthreads();

    // ---- FC: out[b] = h2[b] . fcW + fcb ----
    if (tid < 256) {
        const int b = tid >> 4, l = tid & 15;
        float p = 0.f;
        for (int jj = l; jj < HH; jj += 16)
            p = __builtin_fmaf(h2s[b * 52 + jj], fcw[jj], p);
        #pragma unroll
        for (int off = 8; off > 0; off >>= 1) p += __shfl_xor(p, off, 16);
        if (l == 0) out[b0 + b] = p + fcb[0];
    }
}

extern "C" void kernel_launch(void* const* d_in, const int* in_sizes, int n_in,
                              void* d_out, int out_size, void* d_ws, size_t ws_size,
                              hipStream_t stream) {
    lstm_mfma_kernel<<<NB, 512, 0, stream>>>(
        (const float*)d_in[0],                         // x
        (const float*)d_in[1], (const float*)d_in[2],  // lstm1 Wih, Whh
        (const float*)d_in[3], (const float*)d_in[4],  // lstm1 bih, bhh
        (const float*)d_in[5],                         // lstm2 Wih
        (const float*)d_in[7], (const float*)d_in[8],  // lstm2 bih, bhh
        (const float*)d_in[9], (const float*)d_in[10], // fc W, b
        (float*)d_out);
}